// Round 1
// baseline (104.298 us; speedup 1.0000x reference)
//
#include <hip/hip_runtime.h>
#include <math.h>

#define E_NUMC 100000
#define DIMC 32
#define NEIGHC 16
#define RULESC 8
#define STEPSC 2

// One block (256 threads) per batch element; loops over the 8 rules.
// Tree per (b,r): user -> 16 hop1 (adj[rules[r,0], user]) -> 256 hop2
// (adj[rules[r,1], hop1]).  Phases per rule:
//   A: load 16 hop1 ids
//   B: 256 threads each gather+renorm one hop2 row, butterfly-mean over 16
//   C: 17 entities (hop1 + user) renormed by 8-thread groups -> LDS
//   D: level-0 matvec for the 16 hop1 nodes (relu), + mean1
//   D2: v0 = relu(W [u, mean1] + b), meanv1
//   E: res = tanh(W [v0, meanv1] + b); useru += rw[r]*res
// Final: sigmoid(dot(useru, renorm(emb[item]))).
__global__ __launch_bounds__(256) void rgrec_kernel(
    const int* __restrict__ users, const int* __restrict__ items,
    const int* __restrict__ rules, const int* __restrict__ adj,
    const float* __restrict__ emb, const float* __restrict__ rule_w,
    const float* __restrict__ W, const float* __restrict__ bvec,
    float* __restrict__ out)
{
    const int b = blockIdx.x;
    const int t = threadIdx.x;

    __shared__ float Wt[64][32];      // Wt[d][o] = W[o*64+d]
    __shared__ float bs[32];
    __shared__ float h1s[16][33];     // renormed hop1 vecs (pad 33: no bank conflict)
    __shared__ float mean2[16][33];   // mean of renormed hop2 children per hop1 node
    __shared__ float v1[16][33];      // level-0 output per hop1 node
    __shared__ float u_vec[32];
    __shared__ float mean1[32];
    __shared__ float v0[32];
    __shared__ float meanv1[32];
    __shared__ float useru[32];
    __shared__ int   h1id[16];

    // stage W transposed into LDS
    for (int i = t; i < 64 * 32; i += 256) {
        const int o = i >> 6, d = i & 63;
        Wt[d][o] = W[i];
    }
    if (t < 32) { bs[t] = bvec[t]; useru[t] = 0.0f; }

    // rule_w renorm scale (uniform, cached scalar loads)
    float ss = 0.0f;
#pragma unroll
    for (int i = 0; i < RULESC; ++i) { const float w = rule_w[i]; ss += w * w; }
    const float rws = fminf(1.0f, 1.0f / fmaxf(sqrtf(ss), 1e-7f));

    const int user = users[b];

    for (int r = 0; r < RULESC; ++r) {
        const int rid0 = rules[r * 2 + 0];
        const int rid1 = rules[r * 2 + 1];

        // phase A: hop1 ids
        if (t < 16) h1id[t] = adj[(rid0 * E_NUMC + user) * NEIGHC + t];
        __syncthreads();

        // phase B: hop2 gather + renorm + mean over 16 children (all 256 threads)
        {
            const int m = t >> 4, j = t & 15;
            const int e1 = h1id[m];
            const int e2 = adj[(rid1 * E_NUMC + e1) * NEIGHC + j];
            float v[32];
            const float4* p = (const float4*)(emb + (long)e2 * DIMC);
            float sq = 0.0f;
#pragma unroll
            for (int q = 0; q < 8; ++q) {
                const float4 f = p[q];
                v[q * 4 + 0] = f.x; v[q * 4 + 1] = f.y;
                v[q * 4 + 2] = f.z; v[q * 4 + 3] = f.w;
                sq += f.x * f.x + f.y * f.y + f.z * f.z + f.w * f.w;
            }
            const float s =
                fminf(1.0f, 1.0f / fmaxf(sqrtf(sq), 1e-7f)) * (1.0f / 16.0f);
#pragma unroll
            for (int d = 0; d < 32; ++d) v[d] *= s;
            // butterfly all-reduce over the 16-lane group (in-wave)
#pragma unroll
            for (int st = 1; st < 16; st <<= 1) {
#pragma unroll
                for (int d = 0; d < 32; ++d) v[d] += __shfl_xor(v[d], st, 64);
            }
            mean2[m][j]      = v[j];
            mean2[m][j + 16] = v[j + 16];
        }

        // phase C: hop1 + user embeddings, 8 threads per entity (17 entities)
        if (t < 136) {
            const int g = t >> 3, k = t & 7;
            const int e = (g < 16) ? h1id[g] : user;
            const float4 f = ((const float4*)(emb + (long)e * DIMC))[k];
            float sq = f.x * f.x + f.y * f.y + f.z * f.z + f.w * f.w;
            sq += __shfl_xor(sq, 1, 64);
            sq += __shfl_xor(sq, 2, 64);
            sq += __shfl_xor(sq, 4, 64);
            const float s = fminf(1.0f, 1.0f / fmaxf(sqrtf(sq), 1e-7f));
            if (g < 16) {
                h1s[g][k * 4 + 0] = f.x * s; h1s[g][k * 4 + 1] = f.y * s;
                h1s[g][k * 4 + 2] = f.z * s; h1s[g][k * 4 + 3] = f.w * s;
            } else {
                u_vec[k * 4 + 0] = f.x * s; u_vec[k * 4 + 1] = f.y * s;
                u_vec[k * 4 + 2] = f.z * s; u_vec[k * 4 + 3] = f.w * s;
            }
        }
        __syncthreads();

        // phase D: level-0 matvec for the 16 hop1 nodes (2 outputs per thread)
        {
            const int m = t >> 4, o = t & 15;
            float a0 = bs[o], a1 = bs[o + 16];
#pragma unroll
            for (int d = 0; d < 32; ++d) {
                const float h = h1s[m][d];
                a0 += Wt[d][o] * h;
                a1 += Wt[d][o + 16] * h;
            }
#pragma unroll
            for (int d = 0; d < 32; ++d) {
                const float h = mean2[m][d];
                a0 += Wt[32 + d][o] * h;
                a1 += Wt[32 + d][o + 16] * h;
            }
            v1[m][o]      = fmaxf(a0, 0.0f);
            v1[m][o + 16] = fmaxf(a1, 0.0f);
        }
        if (t < 32) {
            float mn = 0.0f;
#pragma unroll
            for (int m = 0; m < 16; ++m) mn += h1s[m][t];
            mean1[t] = mn * (1.0f / 16.0f);
        }
        __syncthreads();

        // phase D2: v0 = relu(W [u, mean1] + b); meanv1 = mean_m v1[m]
        if (t < 32) {
            float a = bs[t];
#pragma unroll
            for (int d = 0; d < 32; ++d) a += Wt[d][t] * u_vec[d];
#pragma unroll
            for (int d = 0; d < 32; ++d) a += Wt[32 + d][t] * mean1[d];
            v0[t] = fmaxf(a, 0.0f);
            float mv = 0.0f;
#pragma unroll
            for (int m = 0; m < 16; ++m) mv += v1[m][t];
            meanv1[t] = mv * (1.0f / 16.0f);
        }
        __syncthreads();

        // phase E: res = tanh(W [v0, meanv1] + b); accumulate weighted
        if (t < 32) {
            float a = bs[t];
#pragma unroll
            for (int d = 0; d < 32; ++d) a += Wt[d][t] * v0[d];
#pragma unroll
            for (int d = 0; d < 32; ++d) a += Wt[32 + d][t] * meanv1[d];
            useru[t] += rule_w[r] * rws * tanhf(a);
        }
        __syncthreads();
    }

    // final: sigmoid(dot(useru, renorm(emb[item])))
    if (t < 32) {
        const int it = items[b];
        const float x = emb[(long)it * DIMC + t];
        float sq = x * x;
        sq += __shfl_xor(sq, 1, 64);
        sq += __shfl_xor(sq, 2, 64);
        sq += __shfl_xor(sq, 4, 64);
        sq += __shfl_xor(sq, 8, 64);
        sq += __shfl_xor(sq, 16, 64);
        const float s = fminf(1.0f, 1.0f / fmaxf(sqrtf(sq), 1e-7f));
        float p = useru[t] * x * s;
        p += __shfl_xor(p, 1, 64);
        p += __shfl_xor(p, 2, 64);
        p += __shfl_xor(p, 4, 64);
        p += __shfl_xor(p, 8, 64);
        p += __shfl_xor(p, 16, 64);
        if (t == 0) out[b] = 1.0f / (1.0f + expf(-p));
    }
}

extern "C" void kernel_launch(void* const* d_in, const int* in_sizes, int n_in,
                              void* d_out, int out_size, void* d_ws, size_t ws_size,
                              hipStream_t stream) {
    const int*   users  = (const int*)d_in[0];
    const int*   items  = (const int*)d_in[1];
    const int*   rules  = (const int*)d_in[2];
    const int*   adj    = (const int*)d_in[3];
    const float* emb    = (const float*)d_in[4];
    const float* rule_w = (const float*)d_in[5];
    const float* W      = (const float*)d_in[6];
    const float* bvec   = (const float*)d_in[7];
    float*       out    = (float*)d_out;

    const int batch = in_sizes[0];  // 1024
    rgrec_kernel<<<dim3(batch), dim3(256), 0, stream>>>(
        users, items, rules, adj, emb, rule_w, W, bvec, out);
}

// Round 2
// 97.019 us; speedup vs baseline: 1.0750x; 1.0750x over previous
//
#include <hip/hip_runtime.h>
#include <math.h>

#define E_NUMC 100000
#define DIMC 32
#define NEIGHC 16
#define RULESC 8

// ---------------------------------------------------------------------------
// Kernel 1: one (batch, rule) tree per 256-thread block.
//   B: 256 threads each gather+renorm one hop2 row, butterfly-mean over 16
//   C: 17 entities (hop1 + user) renormed by 8-thread groups -> LDS
//   D: level-0 matvec for the 16 hop1 nodes (relu), + mean1
//   D2: v0 = relu(W [u, mean1] + b), meanv1
//   E: res[b][r][:] = tanh(W [v0, meanv1] + b)
// hop1 ids are loaded per-wave and broadcast with __shfl (no barrier needed
// before the hop2 gathers).
// ---------------------------------------------------------------------------
__global__ __launch_bounds__(256) void rgrec_tree_kernel(
    const int* __restrict__ users, const int* __restrict__ rules,
    const int* __restrict__ adj, const float* __restrict__ emb,
    const float* __restrict__ W, const float* __restrict__ bvec,
    float* __restrict__ res)
{
    const int b = blockIdx.x;
    const int r = blockIdx.y;
    const int t = threadIdx.x;
    const int wave = t >> 6, lane = t & 63;

    __shared__ float Wt[64][32];      // Wt[d][o] = W[o*64+d]
    __shared__ float bs[32];
    __shared__ float h1s[16][33];     // renormed hop1 vecs
    __shared__ float mean2[16][33];   // mean of renormed hop2 children
    __shared__ float v1[16][33];      // level-0 output per hop1 node
    __shared__ float u_vec[32];
    __shared__ float mean1[32];
    __shared__ float v0[32];
    __shared__ float meanv1[32];

    const int user = users[b];
    const int rid0 = rules[r * 2 + 0];
    const int rid1 = rules[r * 2 + 1];

    // per-wave copy of the 16 hop1 ids (redundant loads hit L1/L2, no barrier)
    int h1v = 0;
    if (lane < 16) h1v = adj[(rid0 * E_NUMC + user) * NEIGHC + lane];

    // stage W transposed into LDS (float4 reads)
    {
        const float4* W4 = (const float4*)W;
        for (int i = t; i < 512; i += 256) {
            const float4 f = W4[i];
            const int o = i >> 4, d0 = (i & 15) * 4;
            Wt[d0][o] = f.x; Wt[d0 + 1][o] = f.y;
            Wt[d0 + 2][o] = f.z; Wt[d0 + 3][o] = f.w;
        }
    }
    if (t < 32) bs[t] = bvec[t];

    // ---- phase B ids: m = t>>4 (global node), j = t&15 (child) ----
    const int m = t >> 4;
    const int j = lane & 15;
    const int e1 = __shfl(h1v, (wave << 2) + (lane >> 4), 64);
    const int e2 = adj[(rid1 * E_NUMC + e1) * NEIGHC + j];

    // ---- phase C loads issued early (overlap with hop2 gathers) ----
    const int g = t >> 3, k = t & 7;
    const bool cact = (t < 136);
    float4 fc = make_float4(0.f, 0.f, 0.f, 0.f);
    if (cact) {
        int ec;
        if (g < 16) ec = __shfl(h1v, (lane >> 3) + ((t >> 6) << 3), 64);
        else        ec = user;
        fc = ((const float4*)(emb + (long)ec * DIMC))[k];
    }

    // ---- phase B: gather + renorm + butterfly mean over 16 children ----
    {
        float v[32];
        const float4* p = (const float4*)(emb + (long)e2 * DIMC);
        float sq = 0.0f;
#pragma unroll
        for (int q = 0; q < 8; ++q) {
            const float4 f = p[q];
            v[q * 4 + 0] = f.x; v[q * 4 + 1] = f.y;
            v[q * 4 + 2] = f.z; v[q * 4 + 3] = f.w;
            sq += f.x * f.x + f.y * f.y + f.z * f.z + f.w * f.w;
        }
        const float s =
            fminf(1.0f, 1.0f / fmaxf(sqrtf(sq), 1e-7f)) * (1.0f / 16.0f);
#pragma unroll
        for (int d = 0; d < 32; ++d) v[d] *= s;
#pragma unroll
        for (int st = 1; st < 16; st <<= 1) {
#pragma unroll
            for (int d = 0; d < 32; ++d) v[d] += __shfl_xor(v[d], st, 64);
        }
        mean2[m][j]      = v[j];
        mean2[m][j + 16] = v[j + 16];
    }

    // ---- phase C: renorm hop1 + user, write LDS ----
    if (cact) {
        float sq = fc.x * fc.x + fc.y * fc.y + fc.z * fc.z + fc.w * fc.w;
        sq += __shfl_xor(sq, 1, 64);
        sq += __shfl_xor(sq, 2, 64);
        sq += __shfl_xor(sq, 4, 64);
        const float s = fminf(1.0f, 1.0f / fmaxf(sqrtf(sq), 1e-7f));
        if (g < 16) {
            h1s[g][k * 4 + 0] = fc.x * s; h1s[g][k * 4 + 1] = fc.y * s;
            h1s[g][k * 4 + 2] = fc.z * s; h1s[g][k * 4 + 3] = fc.w * s;
        } else {
            u_vec[k * 4 + 0] = fc.x * s; u_vec[k * 4 + 1] = fc.y * s;
            u_vec[k * 4 + 2] = fc.z * s; u_vec[k * 4 + 3] = fc.w * s;
        }
    }
    __syncthreads();

    // ---- phase D: level-0 matvec for 16 hop1 nodes (2 outputs/thread) ----
    {
        const int mm = t >> 4, o = t & 15;
        float a0 = bs[o], a1 = bs[o + 16];
#pragma unroll
        for (int d = 0; d < 32; ++d) {
            const float h = h1s[mm][d];
            a0 += Wt[d][o] * h;
            a1 += Wt[d][o + 16] * h;
        }
#pragma unroll
        for (int d = 0; d < 32; ++d) {
            const float h = mean2[mm][d];
            a0 += Wt[32 + d][o] * h;
            a1 += Wt[32 + d][o + 16] * h;
        }
        v1[mm][o]      = fmaxf(a0, 0.0f);
        v1[mm][o + 16] = fmaxf(a1, 0.0f);
    }
    if (t < 32) {
        float mn = 0.0f;
#pragma unroll
        for (int mm = 0; mm < 16; ++mm) mn += h1s[mm][t];
        mean1[t] = mn * (1.0f / 16.0f);
    }
    __syncthreads();

    // ---- phase D2 ----
    if (t < 32) {
        float a = bs[t];
#pragma unroll
        for (int d = 0; d < 32; ++d) a += Wt[d][t] * u_vec[d];
#pragma unroll
        for (int d = 0; d < 32; ++d) a += Wt[32 + d][t] * mean1[d];
        v0[t] = fmaxf(a, 0.0f);
        float mv = 0.0f;
#pragma unroll
        for (int mm = 0; mm < 16; ++mm) mv += v1[mm][t];
        meanv1[t] = mv * (1.0f / 16.0f);
    }
    __syncthreads();

    // ---- phase E ----
    if (t < 32) {
        float a = bs[t];
#pragma unroll
        for (int d = 0; d < 32; ++d) a += Wt[d][t] * v0[d];
#pragma unroll
        for (int d = 0; d < 32; ++d) a += Wt[32 + d][t] * meanv1[d];
        res[(b * RULESC + r) * DIMC + t] = tanhf(a);
    }
}

// ---------------------------------------------------------------------------
// Kernel 2: one wave per batch element — rule-weighted sum + item dot+sigmoid
// ---------------------------------------------------------------------------
__global__ __launch_bounds__(256) void rgrec_combine_kernel(
    const int* __restrict__ items, const float* __restrict__ emb,
    const float* __restrict__ rule_w, const float* __restrict__ res,
    float* __restrict__ out, int B)
{
    const int gw = (blockIdx.x * 256 + threadIdx.x) >> 6;
    const int lane = threadIdx.x & 63;
    if (gw >= B) return;
    const int b = gw;

    float ss = 0.0f;
#pragma unroll
    for (int i = 0; i < RULESC; ++i) { const float w = rule_w[i]; ss += w * w; }
    const float rws = fminf(1.0f, 1.0f / fmaxf(sqrtf(ss), 1e-7f));

    const int d = lane & 31, rh = lane >> 5;
    float acc = 0.0f;
#pragma unroll
    for (int rr = 0; rr < 4; ++rr) {
        const int r = rh * 4 + rr;
        acc += rule_w[r] * res[(b * RULESC + r) * DIMC + d];
    }
    acc += __shfl_xor(acc, 32, 64);
    acc *= rws;

    const int it = items[b];
    const float x = emb[(long)it * DIMC + d];
    float sq = x * x;
    sq += __shfl_xor(sq, 1, 64);
    sq += __shfl_xor(sq, 2, 64);
    sq += __shfl_xor(sq, 4, 64);
    sq += __shfl_xor(sq, 8, 64);
    sq += __shfl_xor(sq, 16, 64);
    const float s = fminf(1.0f, 1.0f / fmaxf(sqrtf(sq), 1e-7f));
    float p = acc * x * s;
    p += __shfl_xor(p, 1, 64);
    p += __shfl_xor(p, 2, 64);
    p += __shfl_xor(p, 4, 64);
    p += __shfl_xor(p, 8, 64);
    p += __shfl_xor(p, 16, 64);
    if (lane == 0) out[b] = 1.0f / (1.0f + expf(-p));
}

// ---------------------------------------------------------------------------
// Fallback (round-1 fused kernel) if d_ws is too small.
// ---------------------------------------------------------------------------
__global__ __launch_bounds__(256) void rgrec_fused_kernel(
    const int* __restrict__ users, const int* __restrict__ items,
    const int* __restrict__ rules, const int* __restrict__ adj,
    const float* __restrict__ emb, const float* __restrict__ rule_w,
    const float* __restrict__ W, const float* __restrict__ bvec,
    float* __restrict__ out)
{
    const int b = blockIdx.x;
    const int t = threadIdx.x;

    __shared__ float Wt[64][32];
    __shared__ float bs[32];
    __shared__ float h1s[16][33];
    __shared__ float mean2[16][33];
    __shared__ float v1[16][33];
    __shared__ float u_vec[32];
    __shared__ float mean1[32];
    __shared__ float v0[32];
    __shared__ float meanv1[32];
    __shared__ float useru[32];
    __shared__ int   h1id[16];

    for (int i = t; i < 64 * 32; i += 256) {
        const int o = i >> 6, d = i & 63;
        Wt[d][o] = W[i];
    }
    if (t < 32) { bs[t] = bvec[t]; useru[t] = 0.0f; }

    float ss = 0.0f;
#pragma unroll
    for (int i = 0; i < RULESC; ++i) { const float w = rule_w[i]; ss += w * w; }
    const float rws = fminf(1.0f, 1.0f / fmaxf(sqrtf(ss), 1e-7f));

    const int user = users[b];

    for (int r = 0; r < RULESC; ++r) {
        const int rid0 = rules[r * 2 + 0];
        const int rid1 = rules[r * 2 + 1];
        if (t < 16) h1id[t] = adj[(rid0 * E_NUMC + user) * NEIGHC + t];
        __syncthreads();
        {
            const int m = t >> 4, j = t & 15;
            const int e1 = h1id[m];
            const int e2 = adj[(rid1 * E_NUMC + e1) * NEIGHC + j];
            float v[32];
            const float4* p = (const float4*)(emb + (long)e2 * DIMC);
            float sq = 0.0f;
#pragma unroll
            for (int q = 0; q < 8; ++q) {
                const float4 f = p[q];
                v[q * 4 + 0] = f.x; v[q * 4 + 1] = f.y;
                v[q * 4 + 2] = f.z; v[q * 4 + 3] = f.w;
                sq += f.x * f.x + f.y * f.y + f.z * f.z + f.w * f.w;
            }
            const float s =
                fminf(1.0f, 1.0f / fmaxf(sqrtf(sq), 1e-7f)) * (1.0f / 16.0f);
#pragma unroll
            for (int d = 0; d < 32; ++d) v[d] *= s;
#pragma unroll
            for (int st = 1; st < 16; st <<= 1) {
#pragma unroll
                for (int d = 0; d < 32; ++d) v[d] += __shfl_xor(v[d], st, 64);
            }
            mean2[m][j]      = v[j];
            mean2[m][j + 16] = v[j + 16];
        }
        if (t < 136) {
            const int g = t >> 3, k = t & 7;
            const int e = (g < 16) ? h1id[g] : user;
            const float4 f = ((const float4*)(emb + (long)e * DIMC))[k];
            float sq = f.x * f.x + f.y * f.y + f.z * f.z + f.w * f.w;
            sq += __shfl_xor(sq, 1, 64);
            sq += __shfl_xor(sq, 2, 64);
            sq += __shfl_xor(sq, 4, 64);
            const float s = fminf(1.0f, 1.0f / fmaxf(sqrtf(sq), 1e-7f));
            if (g < 16) {
                h1s[g][k * 4 + 0] = f.x * s; h1s[g][k * 4 + 1] = f.y * s;
                h1s[g][k * 4 + 2] = f.z * s; h1s[g][k * 4 + 3] = f.w * s;
            } else {
                u_vec[k * 4 + 0] = f.x * s; u_vec[k * 4 + 1] = f.y * s;
                u_vec[k * 4 + 2] = f.z * s; u_vec[k * 4 + 3] = f.w * s;
            }
        }
        __syncthreads();
        {
            const int m = t >> 4, o = t & 15;
            float a0 = bs[o], a1 = bs[o + 16];
#pragma unroll
            for (int d = 0; d < 32; ++d) {
                const float h = h1s[m][d];
                a0 += Wt[d][o] * h;
                a1 += Wt[d][o + 16] * h;
            }
#pragma unroll
            for (int d = 0; d < 32; ++d) {
                const float h = mean2[m][d];
                a0 += Wt[32 + d][o] * h;
                a1 += Wt[32 + d][o + 16] * h;
            }
            v1[m][o]      = fmaxf(a0, 0.0f);
            v1[m][o + 16] = fmaxf(a1, 0.0f);
        }
        if (t < 32) {
            float mn = 0.0f;
#pragma unroll
            for (int m2 = 0; m2 < 16; ++m2) mn += h1s[m2][t];
            mean1[t] = mn * (1.0f / 16.0f);
        }
        __syncthreads();
        if (t < 32) {
            float a = bs[t];
#pragma unroll
            for (int d = 0; d < 32; ++d) a += Wt[d][t] * u_vec[d];
#pragma unroll
            for (int d = 0; d < 32; ++d) a += Wt[32 + d][t] * mean1[d];
            v0[t] = fmaxf(a, 0.0f);
            float mv = 0.0f;
#pragma unroll
            for (int m2 = 0; m2 < 16; ++m2) mv += v1[m2][t];
            meanv1[t] = mv * (1.0f / 16.0f);
        }
        __syncthreads();
        if (t < 32) {
            float a = bs[t];
#pragma unroll
            for (int d = 0; d < 32; ++d) a += Wt[d][t] * v0[d];
#pragma unroll
            for (int d = 0; d < 32; ++d) a += Wt[32 + d][t] * meanv1[d];
            useru[t] += rule_w[r] * rws * tanhf(a);
        }
        __syncthreads();
    }

    if (t < 32) {
        const int it = items[b];
        const float x = emb[(long)it * DIMC + t];
        float sq = x * x;
        sq += __shfl_xor(sq, 1, 64);
        sq += __shfl_xor(sq, 2, 64);
        sq += __shfl_xor(sq, 4, 64);
        sq += __shfl_xor(sq, 8, 64);
        sq += __shfl_xor(sq, 16, 64);
        const float s = fminf(1.0f, 1.0f / fmaxf(sqrtf(sq), 1e-7f));
        float p = useru[t] * x * s;
        p += __shfl_xor(p, 1, 64);
        p += __shfl_xor(p, 2, 64);
        p += __shfl_xor(p, 4, 64);
        p += __shfl_xor(p, 8, 64);
        p += __shfl_xor(p, 16, 64);
        if (t == 0) out[b] = 1.0f / (1.0f + expf(-p));
    }
}

extern "C" void kernel_launch(void* const* d_in, const int* in_sizes, int n_in,
                              void* d_out, int out_size, void* d_ws, size_t ws_size,
                              hipStream_t stream) {
    const int*   users  = (const int*)d_in[0];
    const int*   items  = (const int*)d_in[1];
    const int*   rules  = (const int*)d_in[2];
    const int*   adj    = (const int*)d_in[3];
    const float* emb    = (const float*)d_in[4];
    const float* rule_w = (const float*)d_in[5];
    const float* W      = (const float*)d_in[6];
    const float* bvec   = (const float*)d_in[7];
    float*       out    = (float*)d_out;

    const int batch = in_sizes[0];  // 1024
    const size_t need = (size_t)batch * RULESC * DIMC * sizeof(float);

    if (ws_size >= need) {
        float* res = (float*)d_ws;
        rgrec_tree_kernel<<<dim3(batch, RULESC), dim3(256), 0, stream>>>(
            users, rules, adj, emb, W, bvec, res);
        const int nblk = (batch * 64 + 255) / 256;
        rgrec_combine_kernel<<<dim3(nblk), dim3(256), 0, stream>>>(
            items, emb, rule_w, res, out, batch);
    } else {
        rgrec_fused_kernel<<<dim3(batch), dim3(256), 0, stream>>>(
            users, items, rules, adj, emb, rule_w, W, bvec, out);
    }
}

// Round 3
// 69.388 us; speedup vs baseline: 1.5031x; 1.3982x over previous
//
#include <hip/hip_runtime.h>
#include <hip/hip_fp16.h>
#include <math.h>

#define E_NUMC 100000
#define DIMC 32
#define NEIGHC 16
#define RULESC 8

// ---------------------------------------------------------------------------
// Pre-pass: renormed fp16 embedding table in d_ws.
// emb16[i][d] = fp16( emb[i][d] * min(1, 1/max(||emb[i]||, 1e-7)) )
// ---------------------------------------------------------------------------
__global__ __launch_bounds__(256) void renorm_f16_kernel(
    const float* __restrict__ emb, __half2* __restrict__ o16, int n)
{
    const int i = blockIdx.x * 256 + threadIdx.x;
    if (i >= n) return;
    const float4* p = (const float4*)(emb + (long)i * DIMC);
    float v[32];
    float sq = 0.0f;
#pragma unroll
    for (int q = 0; q < 8; ++q) {
        const float4 f = p[q];
        v[q * 4 + 0] = f.x; v[q * 4 + 1] = f.y;
        v[q * 4 + 2] = f.z; v[q * 4 + 3] = f.w;
        sq += f.x * f.x + f.y * f.y + f.z * f.z + f.w * f.w;
    }
    const float s = fminf(1.0f, 1.0f / fmaxf(sqrtf(sq), 1e-7f));
    __half2* o = o16 + (long)i * (DIMC / 2);
#pragma unroll
    for (int k = 0; k < 16; ++k)
        o[k] = __floats2half2_rn(v[2 * k] * s, v[2 * k + 1] * s);
}

// ---------------------------------------------------------------------------
// Kernel 1: one (batch, rule) tree per 256-thread block, fp16 renormed table.
// Phase B: thread (m = t>>4, j = t&15) owns dims (2j, 2j+1) and accumulates
// them over the 16 hop2 children of node m straight from global memory
// (coalesced 64-B row reads, no butterfly shuffles, no per-gather renorm).
// ---------------------------------------------------------------------------
__global__ __launch_bounds__(256) void rgrec_tree16_kernel(
    const int* __restrict__ users, const int* __restrict__ rules,
    const int* __restrict__ adj, const __half2* __restrict__ emb16,
    const float* __restrict__ W, const float* __restrict__ bvec,
    float* __restrict__ res)
{
    const int b = blockIdx.x;
    const int r = blockIdx.y;
    const int t = threadIdx.x;
    const int lane = t & 63;

    __shared__ float Wt[64][32];      // Wt[d][o] = W[o*64+d]
    __shared__ float bs[32];
    __shared__ float h1s[16][33];     // renormed hop1 vecs
    __shared__ float mean2[16][33];   // mean of renormed hop2 children
    __shared__ float v1[16][33];      // level-0 output per hop1 node
    __shared__ float u_vec[32];
    __shared__ float mean1[32];
    __shared__ float v0[32];
    __shared__ float meanv1[32];

    const int user = users[b];
    const int rid0 = rules[r * 2 + 0];
    const int rid1 = rules[r * 2 + 1];

    // per-wave copy of the 16 hop1 ids (no barrier needed)
    int h1v = 0;
    if (lane < 16) h1v = adj[(rid0 * E_NUMC + user) * NEIGHC + lane];

    // stage W transposed into LDS (float4 reads)
    {
        const float4* W4 = (const float4*)W;
        for (int i = t; i < 512; i += 256) {
            const float4 f = W4[i];
            const int o = i >> 4, d0 = (i & 15) * 4;
            Wt[d0][o] = f.x; Wt[d0 + 1][o] = f.y;
            Wt[d0 + 2][o] = f.z; Wt[d0 + 3][o] = f.w;
        }
    }
    if (t < 32) bs[t] = bvec[t];

    // ---- phase B ids: m = node, j = dim-pair ----
    const int m = t >> 4;
    const int j = t & 15;
    const int e1 = __shfl(h1v, m, 64);                  // m < 16
    const int e2 = adj[(rid1 * E_NUMC + e1) * NEIGHC + j];  // child j's id

    // ---- phase C loads issued early: 17 rows (16 hop1 + user), 8B each ----
    const int g = t >> 3, k = t & 7;   // row g, 4-dim chunk k
    const bool cact = (t < 136);
    __half2 ca = __half2(), cb = __half2();
    if (cact) {
        const int ec = (g < 16) ? __shfl(h1v, g, 64) : user;
        const __half2* rp = emb16 + (long)ec * (DIMC / 2);
        ca = rp[2 * k];
        cb = rp[2 * k + 1];
    }

    // ---- phase B: accumulate dims (2j,2j+1) over 16 children ----
    {
        float accLo = 0.0f, accHi = 0.0f;
        const int gbase = lane & 48;   // lane index of child 0 in this group
#pragma unroll
        for (int c = 0; c < 16; ++c) {
            const int ec = __shfl(e2, gbase + c, 64);
            const float2 f = __half22float2(emb16[(long)ec * (DIMC / 2) + j]);
            accLo += f.x;
            accHi += f.y;
        }
        mean2[m][2 * j]     = accLo * (1.0f / 16.0f);
        mean2[m][2 * j + 1] = accHi * (1.0f / 16.0f);
    }

    // ---- phase C: convert + store hop1/user rows ----
    if (cact) {
        const float2 fa = __half22float2(ca);
        const float2 fb = __half22float2(cb);
        if (g < 16) {
            h1s[g][4 * k + 0] = fa.x; h1s[g][4 * k + 1] = fa.y;
            h1s[g][4 * k + 2] = fb.x; h1s[g][4 * k + 3] = fb.y;
        } else {
            u_vec[4 * k + 0] = fa.x; u_vec[4 * k + 1] = fa.y;
            u_vec[4 * k + 2] = fb.x; u_vec[4 * k + 3] = fb.y;
        }
    }
    __syncthreads();

    // ---- phase D: level-0 matvec for 16 hop1 nodes (2 outputs/thread) ----
    {
        const int mm = t >> 4, o = t & 15;
        float a0 = bs[o], a1 = bs[o + 16];
#pragma unroll
        for (int d = 0; d < 32; ++d) {
            const float h = h1s[mm][d];
            a0 += Wt[d][o] * h;
            a1 += Wt[d][o + 16] * h;
        }
#pragma unroll
        for (int d = 0; d < 32; ++d) {
            const float h = mean2[mm][d];
            a0 += Wt[32 + d][o] * h;
            a1 += Wt[32 + d][o + 16] * h;
        }
        v1[mm][o]      = fmaxf(a0, 0.0f);
        v1[mm][o + 16] = fmaxf(a1, 0.0f);
    }
    if (t < 32) {
        float mn = 0.0f;
#pragma unroll
        for (int mm = 0; mm < 16; ++mm) mn += h1s[mm][t];
        mean1[t] = mn * (1.0f / 16.0f);
    }
    __syncthreads();

    // ---- phase D2 ----
    if (t < 32) {
        float a = bs[t];
#pragma unroll
        for (int d = 0; d < 32; ++d) a += Wt[d][t] * u_vec[d];
#pragma unroll
        for (int d = 0; d < 32; ++d) a += Wt[32 + d][t] * mean1[d];
        v0[t] = fmaxf(a, 0.0f);
        float mv = 0.0f;
#pragma unroll
        for (int mm = 0; mm < 16; ++mm) mv += v1[mm][t];
        meanv1[t] = mv * (1.0f / 16.0f);
    }
    __syncthreads();

    // ---- phase E ----
    if (t < 32) {
        float a = bs[t];
#pragma unroll
        for (int d = 0; d < 32; ++d) a += Wt[d][t] * v0[d];
#pragma unroll
        for (int d = 0; d < 32; ++d) a += Wt[32 + d][t] * meanv1[d];
        res[(b * RULESC + r) * DIMC + t] = tanhf(a);
    }
}

// ---------------------------------------------------------------------------
// Kernel 2: one wave per batch element — rule-weighted sum + item dot+sigmoid
// (item row renormed from the ORIGINAL fp32 table for final accuracy)
// ---------------------------------------------------------------------------
__global__ __launch_bounds__(256) void rgrec_combine_kernel(
    const int* __restrict__ items, const float* __restrict__ emb,
    const float* __restrict__ rule_w, const float* __restrict__ res,
    float* __restrict__ out, int B)
{
    const int gw = (blockIdx.x * 256 + threadIdx.x) >> 6;
    const int lane = threadIdx.x & 63;
    if (gw >= B) return;
    const int b = gw;

    float ss = 0.0f;
#pragma unroll
    for (int i = 0; i < RULESC; ++i) { const float w = rule_w[i]; ss += w * w; }
    const float rws = fminf(1.0f, 1.0f / fmaxf(sqrtf(ss), 1e-7f));

    const int d = lane & 31, rh = lane >> 5;
    float acc = 0.0f;
#pragma unroll
    for (int rr = 0; rr < 4; ++rr) {
        const int r = rh * 4 + rr;
        acc += rule_w[r] * res[(b * RULESC + r) * DIMC + d];
    }
    acc += __shfl_xor(acc, 32, 64);
    acc *= rws;

    const int it = items[b];
    const float x = emb[(long)it * DIMC + d];
    float sq = x * x;
    sq += __shfl_xor(sq, 1, 64);
    sq += __shfl_xor(sq, 2, 64);
    sq += __shfl_xor(sq, 4, 64);
    sq += __shfl_xor(sq, 8, 64);
    sq += __shfl_xor(sq, 16, 64);
    const float s = fminf(1.0f, 1.0f / fmaxf(sqrtf(sq), 1e-7f));
    float p = acc * x * s;
    p += __shfl_xor(p, 1, 64);
    p += __shfl_xor(p, 2, 64);
    p += __shfl_xor(p, 4, 64);
    p += __shfl_xor(p, 8, 64);
    p += __shfl_xor(p, 16, 64);
    if (lane == 0) out[b] = 1.0f / (1.0f + expf(-p));
}

// ---------------------------------------------------------------------------
// Fallback fused fp32 kernel (known-good) if d_ws is too small.
// ---------------------------------------------------------------------------
__global__ __launch_bounds__(256) void rgrec_fused_kernel(
    const int* __restrict__ users, const int* __restrict__ items,
    const int* __restrict__ rules, const int* __restrict__ adj,
    const float* __restrict__ emb, const float* __restrict__ rule_w,
    const float* __restrict__ W, const float* __restrict__ bvec,
    float* __restrict__ out)
{
    const int b = blockIdx.x;
    const int t = threadIdx.x;

    __shared__ float Wt[64][32];
    __shared__ float bs[32];
    __shared__ float h1s[16][33];
    __shared__ float mean2[16][33];
    __shared__ float v1[16][33];
    __shared__ float u_vec[32];
    __shared__ float mean1[32];
    __shared__ float v0[32];
    __shared__ float meanv1[32];
    __shared__ float useru[32];
    __shared__ int   h1id[16];

    for (int i = t; i < 64 * 32; i += 256) {
        const int o = i >> 6, d = i & 63;
        Wt[d][o] = W[i];
    }
    if (t < 32) { bs[t] = bvec[t]; useru[t] = 0.0f; }

    float ss = 0.0f;
#pragma unroll
    for (int i = 0; i < RULESC; ++i) { const float w = rule_w[i]; ss += w * w; }
    const float rws = fminf(1.0f, 1.0f / fmaxf(sqrtf(ss), 1e-7f));

    const int user = users[b];

    for (int r = 0; r < RULESC; ++r) {
        const int rid0 = rules[r * 2 + 0];
        const int rid1 = rules[r * 2 + 1];
        if (t < 16) h1id[t] = adj[(rid0 * E_NUMC + user) * NEIGHC + t];
        __syncthreads();
        {
            const int m = t >> 4, j = t & 15;
            const int e1 = h1id[m];
            const int e2 = adj[(rid1 * E_NUMC + e1) * NEIGHC + j];
            float v[32];
            const float4* p = (const float4*)(emb + (long)e2 * DIMC);
            float sq = 0.0f;
#pragma unroll
            for (int q = 0; q < 8; ++q) {
                const float4 f = p[q];
                v[q * 4 + 0] = f.x; v[q * 4 + 1] = f.y;
                v[q * 4 + 2] = f.z; v[q * 4 + 3] = f.w;
                sq += f.x * f.x + f.y * f.y + f.z * f.z + f.w * f.w;
            }
            const float s =
                fminf(1.0f, 1.0f / fmaxf(sqrtf(sq), 1e-7f)) * (1.0f / 16.0f);
#pragma unroll
            for (int d = 0; d < 32; ++d) v[d] *= s;
#pragma unroll
            for (int st = 1; st < 16; st <<= 1) {
#pragma unroll
                for (int d = 0; d < 32; ++d) v[d] += __shfl_xor(v[d], st, 64);
            }
            mean2[m][j]      = v[j];
            mean2[m][j + 16] = v[j + 16];
        }
        if (t < 136) {
            const int g = t >> 3, k = t & 7;
            const int e = (g < 16) ? h1id[g] : user;
            const float4 f = ((const float4*)(emb + (long)e * DIMC))[k];
            float sq = f.x * f.x + f.y * f.y + f.z * f.z + f.w * f.w;
            sq += __shfl_xor(sq, 1, 64);
            sq += __shfl_xor(sq, 2, 64);
            sq += __shfl_xor(sq, 4, 64);
            const float s = fminf(1.0f, 1.0f / fmaxf(sqrtf(sq), 1e-7f));
            if (g < 16) {
                h1s[g][k * 4 + 0] = f.x * s; h1s[g][k * 4 + 1] = f.y * s;
                h1s[g][k * 4 + 2] = f.z * s; h1s[g][k * 4 + 3] = f.w * s;
            } else {
                u_vec[k * 4 + 0] = f.x * s; u_vec[k * 4 + 1] = f.y * s;
                u_vec[k * 4 + 2] = f.z * s; u_vec[k * 4 + 3] = f.w * s;
            }
        }
        __syncthreads();
        {
            const int m = t >> 4, o = t & 15;
            float a0 = bs[o], a1 = bs[o + 16];
#pragma unroll
            for (int d = 0; d < 32; ++d) {
                const float h = h1s[m][d];
                a0 += Wt[d][o] * h;
                a1 += Wt[d][o + 16] * h;
            }
#pragma unroll
            for (int d = 0; d < 32; ++d) {
                const float h = mean2[m][d];
                a0 += Wt[32 + d][o] * h;
                a1 += Wt[32 + d][o + 16] * h;
            }
            v1[m][o]      = fmaxf(a0, 0.0f);
            v1[m][o + 16] = fmaxf(a1, 0.0f);
        }
        if (t < 32) {
            float mn = 0.0f;
#pragma unroll
            for (int m2 = 0; m2 < 16; ++m2) mn += h1s[m2][t];
            mean1[t] = mn * (1.0f / 16.0f);
        }
        __syncthreads();
        if (t < 32) {
            float a = bs[t];
#pragma unroll
            for (int d = 0; d < 32; ++d) a += Wt[d][t] * u_vec[d];
#pragma unroll
            for (int d = 0; d < 32; ++d) a += Wt[32 + d][t] * mean1[d];
            v0[t] = fmaxf(a, 0.0f);
            float mv = 0.0f;
#pragma unroll
            for (int m2 = 0; m2 < 16; ++m2) mv += v1[m2][t];
            meanv1[t] = mv * (1.0f / 16.0f);
        }
        __syncthreads();
        if (t < 32) {
            float a = bs[t];
#pragma unroll
            for (int d = 0; d < 32; ++d) a += Wt[d][t] * v0[d];
#pragma unroll
            for (int d = 0; d < 32; ++d) a += Wt[32 + d][t] * meanv1[d];
            useru[t] += rule_w[r] * rws * tanhf(a);
        }
        __syncthreads();
    }

    if (t < 32) {
        const int it = items[b];
        const float x = emb[(long)it * DIMC + t];
        float sq = x * x;
        sq += __shfl_xor(sq, 1, 64);
        sq += __shfl_xor(sq, 2, 64);
        sq += __shfl_xor(sq, 4, 64);
        sq += __shfl_xor(sq, 8, 64);
        sq += __shfl_xor(sq, 16, 64);
        const float s = fminf(1.0f, 1.0f / fmaxf(sqrtf(sq), 1e-7f));
        float p = useru[t] * x * s;
        p += __shfl_xor(p, 1, 64);
        p += __shfl_xor(p, 2, 64);
        p += __shfl_xor(p, 4, 64);
        p += __shfl_xor(p, 8, 64);
        p += __shfl_xor(p, 16, 64);
        if (t == 0) out[b] = 1.0f / (1.0f + expf(-p));
    }
}

extern "C" void kernel_launch(void* const* d_in, const int* in_sizes, int n_in,
                              void* d_out, int out_size, void* d_ws, size_t ws_size,
                              hipStream_t stream) {
    const int*   users  = (const int*)d_in[0];
    const int*   items  = (const int*)d_in[1];
    const int*   rules  = (const int*)d_in[2];
    const int*   adj    = (const int*)d_in[3];
    const float* emb    = (const float*)d_in[4];
    const float* rule_w = (const float*)d_in[5];
    const float* W      = (const float*)d_in[6];
    const float* bvec   = (const float*)d_in[7];
    float*       out    = (float*)d_out;

    const int batch = in_sizes[0];  // 1024
    const size_t emb16_bytes = (size_t)E_NUMC * DIMC * sizeof(__half);  // 6.4 MB
    const size_t res_bytes   = (size_t)batch * RULESC * DIMC * sizeof(float);

    if (ws_size >= emb16_bytes + res_bytes) {
        __half2* emb16 = (__half2*)d_ws;
        float*   res   = (float*)((char*)d_ws + emb16_bytes);

        renorm_f16_kernel<<<dim3((E_NUMC + 255) / 256), dim3(256), 0, stream>>>(
            emb, emb16, E_NUMC);
        rgrec_tree16_kernel<<<dim3(batch, RULESC), dim3(256), 0, stream>>>(
            users, rules, adj, emb16, W, bvec, res);
        const int nblk = (batch * 64 + 255) / 256;
        rgrec_combine_kernel<<<dim3(nblk), dim3(256), 0, stream>>>(
            items, emb, rule_w, res, out, batch);
    } else {
        rgrec_fused_kernel<<<dim3(batch), dim3(256), 0, stream>>>(
            users, items, rules, adj, emb, rule_w, W, bvec, out);
    }
}